// Round 1
// baseline (787.115 us; speedup 1.0000x reference)
//
#include <hip/hip_runtime.h>
#include <hip/hip_bf16.h>
#include <math.h>

#define N_S   512
#define C_S   2048
#define HW_S  128
#define NCLS  751
#define NCLSP 768           // padded to 12*64 for the MFMA GEMM
#define ALPHA 1.2f
#define LAMB  0.5f
#define SIGMA 0.8f
#define BN_EPS 1e-5f

typedef __attribute__((ext_vector_type(8))) short short8;   // 8 bf16 = 4 VGPRs
typedef __attribute__((ext_vector_type(4))) float f32x4;

// ---------------------------------------------------------------- utilities
__device__ __forceinline__ unsigned short f2bf(float x) {
    __hip_bfloat16 h = __float2bfloat16(x);
    return *reinterpret_cast<unsigned short*>(&h);
}

// -------------------------------------------------------------- 0. init accum
__global__ void init_accum_kernel(float* __restrict__ accum) {
    if (threadIdx.x < 4) accum[threadIdx.x] = 0.0f;
}

// -------------------------------------------------------------- 1. avg pool
// features [N, C, H, W] -> gf [N, C]; also write to out+1 (global_feat output).
// 32 lanes per (n,c) pair, each lane one float4 of the 128 spatial elems.
__global__ __launch_bounds__(256) void pool_kernel(const float* __restrict__ feat,
                                                   float* __restrict__ gf,
                                                   float* __restrict__ out_gf) {
    int tid  = blockIdx.x * 256 + threadIdx.x;
    int pair = tid >> 5;          // n*C + c
    int lane = tid & 31;
    const float4* p = reinterpret_cast<const float4*>(feat + (size_t)pair * HW_S);
    float4 v = p[lane];
    float s = v.x + v.y + v.z + v.w;
    #pragma unroll
    for (int off = 16; off > 0; off >>= 1) s += __shfl_down(s, off, 32);
    if (lane == 0) {
        float m = s * (1.0f / HW_S);
        gf[pair]     = m;
        out_gf[pair] = m;
    }
}

// -------------------------------------------------------------- 2. BN stats
__global__ __launch_bounds__(256) void meanvar_kernel(const float* __restrict__ gf,
                                                      const float* __restrict__ gamma,
                                                      float* __restrict__ mu_out,
                                                      float* __restrict__ scale_out) {
    int c = blockIdx.x * 256 + threadIdx.x;
    float sum = 0.f, sumsq = 0.f;
    for (int n = 0; n < N_S; ++n) {
        float x = gf[(size_t)n * C_S + c];
        sum += x; sumsq += x * x;
    }
    float mu  = sum * (1.0f / N_S);
    float var = sumsq * (1.0f / N_S) - mu * mu;
    mu_out[c]    = mu;
    scale_out[c] = gamma[c] / sqrtf(var + BN_EPS);
}

// --------------------------------------------- 3. BN apply + l2norm -> bf16
__global__ __launch_bounds__(256) void bnnorm_kernel(const float* __restrict__ gf,
                                                     const float* __restrict__ mu,
                                                     const float* __restrict__ scale,
                                                     unsigned short* __restrict__ bnnh,
                                                     float* __restrict__ sq) {
    int n = blockIdx.x, t = threadIdx.x;
    const float* row = gf + (size_t)n * C_S;
    float v[8];
    float ss = 0.f;
    #pragma unroll
    for (int k = 0; k < 8; ++k) {
        int c = t + k * 256;
        float x = (row[c] - mu[c]) * scale[c];
        v[k] = x; ss += x * x;
    }
    __shared__ float red[4];
    __shared__ float sinv;
    #pragma unroll
    for (int off = 32; off > 0; off >>= 1) ss += __shfl_down(ss, off, 64);
    if ((t & 63) == 0) red[t >> 6] = ss;
    __syncthreads();
    if (t == 0) {
        float tot = red[0] + red[1] + red[2] + red[3];
        float inv = 1.0f / fmaxf(sqrtf(tot), 1e-12f);
        sinv  = inv;
        sq[n] = tot * inv * inv;    // == sum(bnn^2), ~1.0
    }
    __syncthreads();
    float inv = sinv;
    unsigned short* orow = bnnh + (size_t)n * C_S;
    #pragma unroll
    for (int k = 0; k < 8; ++k) orow[t + k * 256] = f2bf(v[k] * inv);
}

// --------------------------------------- 4. weight row l2norm -> bf16 (padded)
__global__ __launch_bounds__(256) void wnorm_kernel(const float* __restrict__ w,
                                                    unsigned short* __restrict__ wnh) {
    int kcls = blockIdx.x, t = threadIdx.x;
    unsigned short* orow = wnh + (size_t)kcls * C_S;
    if (kcls >= NCLS) {           // zero padding rows 751..767
        #pragma unroll
        for (int k = 0; k < 8; ++k) orow[t + k * 256] = 0;
        return;
    }
    const float* row = w + (size_t)kcls * C_S;
    float v[8];
    float ss = 0.f;
    #pragma unroll
    for (int k = 0; k < 8; ++k) {
        float x = row[t + k * 256];
        v[k] = x; ss += x * x;
    }
    __shared__ float red[4];
    __shared__ float sinv;
    #pragma unroll
    for (int off = 32; off > 0; off >>= 1) ss += __shfl_down(ss, off, 64);
    if ((t & 63) == 0) red[t >> 6] = ss;
    __syncthreads();
    if (t == 0) sinv = 1.0f / fmaxf(sqrtf(red[0] + red[1] + red[2] + red[3]), 1e-12f);
    __syncthreads();
    float inv = sinv;
    #pragma unroll
    for (int k = 0; k < 8; ++k) orow[t + k * 256] = f2bf(v[k] * inv);
}

// ------------------------------------------- 5. bf16 MFMA GEMM: C = A * B^T
// A [M, K] bf16 row-major, B [Nn, K] bf16 row-major. Grid (M/64, Nn/64).
// Block = 4 waves; wave w computes rows [m0+16w, +16) x 64 cols (4 MFMA tiles).
// Fragment layouts (learn_hip m89/m92-verified):
//   A frag: lane holds A[m0 + (lane&15)][k + (lane>>4)*8 + j], j=0..7 (16B contig)
//   B frag: lane holds B^T row n0 + (lane&15), same k addressing
//   C/D:    col = lane&15, row = (lane>>4)*4 + reg
__global__ __launch_bounds__(256) void mfma_gemm_nt(const unsigned short* __restrict__ Ah,
                                                    const unsigned short* __restrict__ Bh,
                                                    float* __restrict__ Cm,
                                                    int K, int ldc) {
    int wave = threadIdx.x >> 6;
    int lane = threadIdx.x & 63;
    int m0 = blockIdx.x * 64 + wave * 16;
    int n0 = blockIdx.y * 64;
    int mrow = m0 + (lane & 15);
    int kq   = (lane >> 4) * 8;
    f32x4 acc0 = {0.f,0.f,0.f,0.f}, acc1 = {0.f,0.f,0.f,0.f};
    f32x4 acc2 = {0.f,0.f,0.f,0.f}, acc3 = {0.f,0.f,0.f,0.f};
    const unsigned short* arow = Ah + (size_t)mrow * K + kq;
    const unsigned short* brow = Bh + (size_t)(n0 + (lane & 15)) * K + kq;
    for (int k = 0; k < K; k += 32) {
        short8 a  = *reinterpret_cast<const short8*>(arow + k);
        short8 b0 = *reinterpret_cast<const short8*>(brow + k);
        short8 b1 = *reinterpret_cast<const short8*>(brow + 16 * K + k);
        short8 b2 = *reinterpret_cast<const short8*>(brow + 32 * K + k);
        short8 b3 = *reinterpret_cast<const short8*>(brow + 48 * K + k);
        acc0 = __builtin_amdgcn_mfma_f32_16x16x32_bf16(a, b0, acc0, 0, 0, 0);
        acc1 = __builtin_amdgcn_mfma_f32_16x16x32_bf16(a, b1, acc1, 0, 0, 0);
        acc2 = __builtin_amdgcn_mfma_f32_16x16x32_bf16(a, b2, acc2, 0, 0, 0);
        acc3 = __builtin_amdgcn_mfma_f32_16x16x32_bf16(a, b3, acc3, 0, 0, 0);
    }
    int ccol  = lane & 15;
    int crow0 = m0 + (lane >> 4) * 4;
    #pragma unroll
    for (int r = 0; r < 4; ++r) {
        float* orow = Cm + (size_t)(crow0 + r) * ldc + n0 + ccol;
        orow[0]  = acc0[r];
        orow[16] = acc1[r];
        orow[32] = acc2[r];
        orow[48] = acc3[r];
    }
}

// ---------------------------------------------- 6. softmax -> atten[n]
__global__ __launch_bounds__(256) void softmax_atten_kernel(const float* __restrict__ logits,
                                                            const int* __restrict__ targets,
                                                            float* __restrict__ atten) {
    int n = blockIdx.x, t = threadIdx.x;
    const float* row = logits + (size_t)n * NCLSP;
    __shared__ float red[4];
    __shared__ float srmax, srsum;
    float m = -1e30f;
    for (int k = t; k < NCLS; k += 256) m = fmaxf(m, row[k]);
    #pragma unroll
    for (int off = 32; off > 0; off >>= 1) m = fmaxf(m, __shfl_down(m, off, 64));
    if ((t & 63) == 0) red[t >> 6] = m;
    __syncthreads();
    if (t == 0) srmax = fmaxf(fmaxf(red[0], red[1]), fmaxf(red[2], red[3]));
    __syncthreads();
    float rm = srmax;
    float s = 0.f;
    for (int k = t; k < NCLS; k += 256) s += expf(row[k] - rm);
    #pragma unroll
    for (int off = 32; off > 0; off >>= 1) s += __shfl_down(s, off, 64);
    if ((t & 63) == 0) red[t >> 6] = s;
    __syncthreads();
    if (t == 0) {
        srsum = red[0] + red[1] + red[2] + red[3];
        atten[n] = expf(row[targets[n]] - rm) / srsum;
    }
}

// ------------------------------------------ 7. pairwise loss reduction
__global__ __launch_bounds__(256) void pair_reduce_kernel(const float* __restrict__ G,
                                                          const float* __restrict__ sq,
                                                          const float* __restrict__ atten,
                                                          const int* __restrict__ targets,
                                                          float* __restrict__ accum) {
    float numP = 0.f, denP = 0.f, numN = 0.f, denN = 0.f;
    const float inv_sig2 = 1.0f / (SIGMA * SIGMA);
    for (int p = blockIdx.x * 256 + threadIdx.x; p < N_S * N_S; p += 256 * 256) {
        int i = p >> 9, j = p & (N_S - 1);
        if (i == j) continue;                    // off-diagonal mask
        float d2   = fmaxf(sq[i] + sq[j] - 2.0f * G[p], 1e-12f);
        float dist = sqrtf(d2);
        float sneg = fmaxf(ALPHA - dist, 1e-12f);
        float Aij  = fminf(atten[i], atten[j]);
        if (targets[i] == targets[j]) {
            float Wm = expf(-d2 * inv_sig2) * Aij;
            numP += Wm * d2; denP += Wm;
        } else {
            float Wm = sneg * Aij;
            numN += Wm * sneg * sneg; denN += Wm;
        }
    }
    #pragma unroll
    for (int off = 32; off > 0; off >>= 1) {
        numP += __shfl_down(numP, off, 64);
        denP += __shfl_down(denP, off, 64);
        numN += __shfl_down(numN, off, 64);
        denN += __shfl_down(denN, off, 64);
    }
    __shared__ float red[4][4];
    int t = threadIdx.x;
    if ((t & 63) == 0) {
        int w = t >> 6;
        red[w][0] = numP; red[w][1] = denP; red[w][2] = numN; red[w][3] = denN;
    }
    __syncthreads();
    if (t < 4) {
        float s = red[0][t] + red[1][t] + red[2][t] + red[3][t];
        atomicAdd(&accum[t], s);
    }
}

// ------------------------------------------------------------- 8. finalize
__global__ void finalize_kernel(const float* __restrict__ accum, float* __restrict__ out) {
    float L_P = 0.5f * accum[0] / accum[1];
    float L_N = 0.5f * accum[2] / accum[3];
    out[0] = (1.0f - LAMB) * L_P + LAMB * L_N;
}

// ---------------------------------------------------------------- launcher
extern "C" void kernel_launch(void* const* d_in, const int* in_sizes, int n_in,
                              void* d_out, int out_size, void* d_ws, size_t ws_size,
                              hipStream_t stream) {
    const float* features = (const float*)d_in[0];
    const int*   targets  = (const int*)d_in[1];
    const float* gamma    = (const float*)d_in[2];
    const float* weight   = (const float*)d_in[3];
    float* out = (float*)d_out;

    // workspace layout (all 16B-aligned segment sizes)
    float* ws     = (float*)d_ws;
    float* gf     = ws;                      // 512*2048          = 1048576
    float* mu     = gf + 1048576;            // 2048
    float* scale  = mu + 2048;               // 2048
    float* sq     = scale + 2048;            // 512
    float* atten  = sq + 512;                // 512
    float* accum  = atten + 512;             // 8 (4 used)
    float* logits = accum + 8;               // 512*768           = 393216
    float* G      = logits + 393216;         // 512*512           = 262144
    unsigned short* bnnh = (unsigned short*)(G + 262144);   // 512*2048 bf16
    unsigned short* wnh  = bnnh + 1048576;                  // 768*2048 bf16
    // total ~12.1 MB

    hipLaunchKernelGGL(init_accum_kernel, dim3(1), dim3(64), 0, stream, accum);
    hipLaunchKernelGGL(pool_kernel, dim3((N_S * C_S) / 8), dim3(256), 0, stream,
                       features, gf, out + 1);
    hipLaunchKernelGGL(meanvar_kernel, dim3(C_S / 256), dim3(256), 0, stream,
                       gf, gamma, mu, scale);
    hipLaunchKernelGGL(bnnorm_kernel, dim3(N_S), dim3(256), 0, stream,
                       gf, mu, scale, bnnh, sq);
    hipLaunchKernelGGL(wnorm_kernel, dim3(NCLSP), dim3(256), 0, stream, weight, wnh);
    hipLaunchKernelGGL(mfma_gemm_nt, dim3(N_S / 64, NCLSP / 64), dim3(256), 0, stream,
                       bnnh, wnh, logits, C_S, NCLSP);
    hipLaunchKernelGGL(softmax_atten_kernel, dim3(N_S), dim3(256), 0, stream,
                       logits, targets, atten);
    hipLaunchKernelGGL(mfma_gemm_nt, dim3(N_S / 64, N_S / 64), dim3(256), 0, stream,
                       bnnh, bnnh, G, C_S, N_S);
    hipLaunchKernelGGL(pair_reduce_kernel, dim3(256), dim3(256), 0, stream,
                       G, sq, atten, targets, accum);
    hipLaunchKernelGGL(finalize_kernel, dim3(1), dim3(1), 0, stream, accum, out);
}

// Round 2
// 746.897 us; speedup vs baseline: 1.0538x; 1.0538x over previous
//
#include <hip/hip_runtime.h>
#include <hip/hip_bf16.h>
#include <math.h>

#define N_S   512
#define C_S   2048
#define HW_S  128
#define NCLS  751
#define NCLSP 768           // padded to 12*64 for the MFMA GEMM
#define ALPHA 1.2f
#define LAMB  0.5f
#define SIGMA 0.8f
#define BN_EPS 1e-5f

typedef __attribute__((ext_vector_type(8))) short short8;   // 8 bf16 = 4 VGPRs
typedef __attribute__((ext_vector_type(4))) float f32x4;

__device__ __forceinline__ unsigned short f2bf(float x) {
    __hip_bfloat16 h = __float2bfloat16(x);
    return *reinterpret_cast<unsigned short*>(&h);
}

// -------------------------------------------------------------- 1. avg pool
// features [N, C, H, W] -> gf [N, C] (written into d_out+1 directly).
// 16 lanes per (n,c) pair; each lane loads 2 float4s (lane, lane+16).
// Block 0 also zero-inits the accum/counter slots (re-poisoned 0xAA each call).
__global__ __launch_bounds__(256) void pool_kernel(const float* __restrict__ feat,
                                                   float* __restrict__ out_gf,
                                                   float* __restrict__ accum) {
    if (blockIdx.x == 0 && threadIdx.x < 8) accum[threadIdx.x] = 0.0f;
    int pair = blockIdx.x * 16 + (threadIdx.x >> 4);   // n*C + c
    int sub  = threadIdx.x & 15;
    const float4* p = reinterpret_cast<const float4*>(feat + (size_t)pair * HW_S);
    float4 v0 = p[sub];
    float4 v1 = p[sub + 16];
    float s = (v0.x + v0.y + v0.z + v0.w) + (v1.x + v1.y + v1.z + v1.w);
    #pragma unroll
    for (int off = 8; off > 0; off >>= 1) s += __shfl_down(s, off, 16);
    if (sub == 0) out_gf[pair] = s * (1.0f / HW_S);
}

// -------------------------------------------------------------- 2. BN stats
// 64 blocks x 256 threads; block handles 32 channels, 8-way row split.
__global__ __launch_bounds__(256) void meanvar_kernel(const float* __restrict__ gf,
                                                      const float* __restrict__ gamma,
                                                      float* __restrict__ mu_out,
                                                      float* __restrict__ scale_out) {
    int tc = threadIdx.x & 31;      // channel within block
    int tr = threadIdx.x >> 5;      // 0..7 row group
    int c  = blockIdx.x * 32 + tc;
    const float* col = gf + c;
    float sum = 0.f, sumsq = 0.f;
    #pragma unroll 4
    for (int n = tr * 64; n < tr * 64 + 64; ++n) {
        float x = col[(size_t)n * C_S];
        sum += x; sumsq += x * x;
    }
    __shared__ float s1[8][32], s2[8][32];
    s1[tr][tc] = sum; s2[tr][tc] = sumsq;
    __syncthreads();
    if (threadIdx.x < 32) {
        int cc = blockIdx.x * 32 + threadIdx.x;
        float a = 0.f, b = 0.f;
        #pragma unroll
        for (int r = 0; r < 8; ++r) { a += s1[r][threadIdx.x]; b += s2[r][threadIdx.x]; }
        float mu  = a * (1.0f / N_S);
        float var = b * (1.0f / N_S) - mu * mu;
        mu_out[cc]    = mu;
        scale_out[cc] = gamma[cc] / sqrtf(var + BN_EPS);
    }
}

// --------------------------------------------- 3. BN apply + l2norm -> bf16
__global__ __launch_bounds__(256) void bnnorm_kernel(const float* __restrict__ gf,
                                                     const float* __restrict__ mu,
                                                     const float* __restrict__ scale,
                                                     unsigned short* __restrict__ bnnh,
                                                     float* __restrict__ sq) {
    int n = blockIdx.x, t = threadIdx.x;
    const float* row = gf + (size_t)n * C_S;
    float v[8];
    float ss = 0.f;
    #pragma unroll
    for (int k = 0; k < 8; ++k) {
        int c = t + k * 256;
        float x = (row[c] - mu[c]) * scale[c];
        v[k] = x; ss += x * x;
    }
    __shared__ float red[4];
    __shared__ float sinv;
    #pragma unroll
    for (int off = 32; off > 0; off >>= 1) ss += __shfl_down(ss, off, 64);
    if ((t & 63) == 0) red[t >> 6] = ss;
    __syncthreads();
    if (t == 0) {
        float tot = red[0] + red[1] + red[2] + red[3];
        float inv = 1.0f / fmaxf(sqrtf(tot), 1e-12f);
        sinv  = inv;
        sq[n] = tot * inv * inv;    // == sum(bnn^2), ~1.0
    }
    __syncthreads();
    float inv = sinv;
    unsigned short* orow = bnnh + (size_t)n * C_S;
    #pragma unroll
    for (int k = 0; k < 8; ++k) orow[t + k * 256] = f2bf(v[k] * inv);
}

// --------------------------------------- 4. weight row l2norm -> bf16 (padded)
__global__ __launch_bounds__(256) void wnorm_kernel(const float* __restrict__ w,
                                                    unsigned short* __restrict__ wnh) {
    int kcls = blockIdx.x, t = threadIdx.x;
    unsigned short* orow = wnh + (size_t)kcls * C_S;
    if (kcls >= NCLS) {           // zero padding rows 751..767
        #pragma unroll
        for (int k = 0; k < 8; ++k) orow[t + k * 256] = 0;
        return;
    }
    const float* row = w + (size_t)kcls * C_S;
    float v[8];
    float ss = 0.f;
    #pragma unroll
    for (int k = 0; k < 8; ++k) {
        float x = row[t + k * 256];
        v[k] = x; ss += x * x;
    }
    __shared__ float red[4];
    __shared__ float sinv;
    #pragma unroll
    for (int off = 32; off > 0; off >>= 1) ss += __shfl_down(ss, off, 64);
    if ((t & 63) == 0) red[t >> 6] = ss;
    __syncthreads();
    if (t == 0) sinv = 1.0f / fmaxf(sqrtf(red[0] + red[1] + red[2] + red[3]), 1e-12f);
    __syncthreads();
    float inv = sinv;
    #pragma unroll
    for (int k = 0; k < 8; ++k) orow[t + k * 256] = f2bf(v[k] * inv);
}

// ------------------------------------------- 5. bf16 MFMA GEMM: C = A * B^T
// One wave per block: 16x64 output tile (4 MFMA accs). Grid (M/16, Nn/64).
// A frag: lane holds A[m0+(lane&15)][k + (lane>>4)*8 + j], j=0..7 (16B contig)
// B frag: lane holds B row n0+(lane&15), same k addressing
// C/D:    col = lane&15, row = (lane>>4)*4 + reg
__global__ __launch_bounds__(64) void mfma_gemm_nt(const unsigned short* __restrict__ Ah,
                                                   const unsigned short* __restrict__ Bh,
                                                   float* __restrict__ Cm,
                                                   int K, int ldc) {
    int lane = threadIdx.x & 63;
    int m0 = blockIdx.x * 16;
    int n0 = blockIdx.y * 64;
    int mrow = m0 + (lane & 15);
    int kq   = (lane >> 4) * 8;
    f32x4 acc0 = {0.f,0.f,0.f,0.f}, acc1 = {0.f,0.f,0.f,0.f};
    f32x4 acc2 = {0.f,0.f,0.f,0.f}, acc3 = {0.f,0.f,0.f,0.f};
    const unsigned short* arow = Ah + (size_t)mrow * K + kq;
    const unsigned short* brow = Bh + (size_t)(n0 + (lane & 15)) * K + kq;
    #pragma unroll 2
    for (int k = 0; k < K; k += 32) {
        short8 a  = *reinterpret_cast<const short8*>(arow + k);
        short8 b0 = *reinterpret_cast<const short8*>(brow + k);
        short8 b1 = *reinterpret_cast<const short8*>(brow + 16 * K + k);
        short8 b2 = *reinterpret_cast<const short8*>(brow + 32 * K + k);
        short8 b3 = *reinterpret_cast<const short8*>(brow + 48 * K + k);
        acc0 = __builtin_amdgcn_mfma_f32_16x16x32_bf16(a, b0, acc0, 0, 0, 0);
        acc1 = __builtin_amdgcn_mfma_f32_16x16x32_bf16(a, b1, acc1, 0, 0, 0);
        acc2 = __builtin_amdgcn_mfma_f32_16x16x32_bf16(a, b2, acc2, 0, 0, 0);
        acc3 = __builtin_amdgcn_mfma_f32_16x16x32_bf16(a, b3, acc3, 0, 0, 0);
    }
    int ccol  = lane & 15;
    int crow0 = m0 + (lane >> 4) * 4;
    #pragma unroll
    for (int r = 0; r < 4; ++r) {
        float* orow = Cm + (size_t)(crow0 + r) * ldc + n0 + ccol;
        orow[0]  = acc0[r];
        orow[16] = acc1[r];
        orow[32] = acc2[r];
        orow[48] = acc3[r];
    }
}

// ---------------------------------------------- 6. softmax -> atten[n]
__global__ __launch_bounds__(256) void softmax_atten_kernel(const float* __restrict__ logits,
                                                            const int* __restrict__ targets,
                                                            float* __restrict__ atten) {
    int n = blockIdx.x, t = threadIdx.x;
    const float* row = logits + (size_t)n * NCLSP;
    __shared__ float red[4];
    __shared__ float srmax, srsum;
    float m = -1e30f;
    for (int k = t; k < NCLS; k += 256) m = fmaxf(m, row[k]);
    #pragma unroll
    for (int off = 32; off > 0; off >>= 1) m = fmaxf(m, __shfl_down(m, off, 64));
    if ((t & 63) == 0) red[t >> 6] = m;
    __syncthreads();
    if (t == 0) srmax = fmaxf(fmaxf(red[0], red[1]), fmaxf(red[2], red[3]));
    __syncthreads();
    float rm = srmax;
    float s = 0.f;
    for (int k = t; k < NCLS; k += 256) s += expf(row[k] - rm);
    #pragma unroll
    for (int off = 32; off > 0; off >>= 1) s += __shfl_down(s, off, 64);
    if ((t & 63) == 0) red[t >> 6] = s;
    __syncthreads();
    if (t == 0) {
        srsum = red[0] + red[1] + red[2] + red[3];
        atten[n] = expf(row[targets[n]] - rm) / srsum;
    }
}

// ------------------------ 7. pairwise loss reduction + fused finalize
// accum[0..3] = {numP, denP, numN, denN}; accum[4] (as uint) = completion ctr.
__global__ __launch_bounds__(256) void pair_reduce_kernel(const float* __restrict__ G,
                                                          const float* __restrict__ sq,
                                                          const float* __restrict__ atten,
                                                          const int* __restrict__ targets,
                                                          float* __restrict__ accum,
                                                          float* __restrict__ out) {
    float numP = 0.f, denP = 0.f, numN = 0.f, denN = 0.f;
    const float inv_sig2 = 1.0f / (SIGMA * SIGMA);
    for (int p = blockIdx.x * 256 + threadIdx.x; p < N_S * N_S; p += 256 * 256) {
        int i = p >> 9, j = p & (N_S - 1);
        if (i == j) continue;                    // off-diagonal mask
        float d2   = fmaxf(sq[i] + sq[j] - 2.0f * G[p], 1e-12f);
        float dist = sqrtf(d2);
        float sneg = fmaxf(ALPHA - dist, 1e-12f);
        float Aij  = fminf(atten[i], atten[j]);
        if (targets[i] == targets[j]) {
            float Wm = expf(-d2 * inv_sig2) * Aij;
            numP += Wm * d2; denP += Wm;
        } else {
            float Wm = sneg * Aij;
            numN += Wm * sneg * sneg; denN += Wm;
        }
    }
    #pragma unroll
    for (int off = 32; off > 0; off >>= 1) {
        numP += __shfl_down(numP, off, 64);
        denP += __shfl_down(denP, off, 64);
        numN += __shfl_down(numN, off, 64);
        denN += __shfl_down(denN, off, 64);
    }
    __shared__ float red[4][4];
    int t = threadIdx.x;
    if ((t & 63) == 0) {
        int w = t >> 6;
        red[w][0] = numP; red[w][1] = denP; red[w][2] = numN; red[w][3] = denN;
    }
    __syncthreads();
    if (t < 4) {
        float s = red[0][t] + red[1][t] + red[2][t] + red[3][t];
        atomicAdd(&accum[t], s);
    }
    __syncthreads();   // all 4 atomics of this block issued & drained before ctr
    if (t == 0) {
        __threadfence();
        unsigned prev = atomicAdd(reinterpret_cast<unsigned*>(accum + 4), 1u);
        if (prev == gridDim.x - 1) {   // last block: finalize
            float a0 = atomicAdd(&accum[0], 0.0f);
            float a1 = atomicAdd(&accum[1], 0.0f);
            float a2 = atomicAdd(&accum[2], 0.0f);
            float a3 = atomicAdd(&accum[3], 0.0f);
            float L_P = 0.5f * a0 / a1;
            float L_N = 0.5f * a2 / a3;
            out[0] = (1.0f - LAMB) * L_P + LAMB * L_N;
        }
    }
}

// ---------------------------------------------------------------- launcher
extern "C" void kernel_launch(void* const* d_in, const int* in_sizes, int n_in,
                              void* d_out, int out_size, void* d_ws, size_t ws_size,
                              hipStream_t stream) {
    const float* features = (const float*)d_in[0];
    const int*   targets  = (const int*)d_in[1];
    const float* gamma    = (const float*)d_in[2];
    const float* weight   = (const float*)d_in[3];
    float* out = (float*)d_out;
    float* gf  = out + 1;                    // global_feat lives in d_out directly

    // workspace layout
    float* ws     = (float*)d_ws;
    float* mu     = ws;                      // 2048
    float* scale  = mu + 2048;               // 2048
    float* sq     = scale + 2048;            // 512
    float* atten  = sq + 512;                // 512
    float* accum  = atten + 512;             // 8 (4 sums + ctr)
    float* logits = accum + 8;               // 512*768 = 393216
    float* G      = logits + 393216;         // 512*512 = 262144
    unsigned short* bnnh = (unsigned short*)(G + 262144);   // 512*2048 bf16
    unsigned short* wnh  = bnnh + 1048576;                  // 768*2048 bf16

    hipLaunchKernelGGL(pool_kernel, dim3((N_S * C_S) / 16), dim3(256), 0, stream,
                       features, gf, accum);
    hipLaunchKernelGGL(meanvar_kernel, dim3(C_S / 32), dim3(256), 0, stream,
                       gf, gamma, mu, scale);
    hipLaunchKernelGGL(bnnorm_kernel, dim3(N_S), dim3(256), 0, stream,
                       gf, mu, scale, bnnh, sq);
    hipLaunchKernelGGL(wnorm_kernel, dim3(NCLSP), dim3(256), 0, stream, weight, wnh);
    hipLaunchKernelGGL(mfma_gemm_nt, dim3(N_S / 16, NCLSP / 64), dim3(64), 0, stream,
                       bnnh, wnh, logits, C_S, NCLSP);
    hipLaunchKernelGGL(softmax_atten_kernel, dim3(N_S), dim3(256), 0, stream,
                       logits, targets, atten);
    hipLaunchKernelGGL(mfma_gemm_nt, dim3(N_S / 16, N_S / 64), dim3(64), 0, stream,
                       bnnh, bnnh, G, C_S, N_S);
    hipLaunchKernelGGL(pair_reduce_kernel, dim3(256), dim3(256), 0, stream,
                       G, sq, atten, targets, accum, out);
}